// Round 11
// baseline (163.150 us; speedup 1.0000x reference)
//
#include <hip/hip_runtime.h>
#include <hip/hip_bf16.h>

// ============================================================================
// R11 = R10 (V through LDS in qkv_proj, -6us) + attn fragment PINNING:
// empty `asm volatile("" : "+v"(frag))` after the 16 ds_read_b128 forces all
// K/V fragments resident (~150 VGPR < 168 cap @ occ-3), so the compiler can
// no longer sink reads into per-pair read->wait->MFMA chains (the R0 codegen:
// VGPR_Count=64 proves frags were never live; every MFMA pair sat behind its
// own LDS round-trip -> CU-wide convoy on the LDS unit, MfmaUtil stuck ~46%).
// Ledger (R1-R8 regressions/failures — do not retry): 32x32 MFMA, kv/q wave
// split, l-on-VALU, setprio (m190 lockstep), cross-tile pipeline (occ-3
// re-sunk / occ-2 spill R7 / race R8).
// ============================================================================

#define B_    4
#define S_    2048
#define HID_  768
#define H_    12
#define DBLK_ 256
#define HD_   64
#define BH_   (B_ * H_)                 // 48
#define QSZ_  (B_ * H_ * S_ * HD_)      // 6291456 elements
#define WTSZ_ (3 * H_ * HD_ * DBLK_)    // 589824 elements

typedef _Float16 f16x4 __attribute__((ext_vector_type(4)));
typedef _Float16 f16x8 __attribute__((ext_vector_type(8)));
typedef float    f32x4 __attribute__((ext_vector_type(4)));

#if __has_builtin(__builtin_amdgcn_exp2f)
#define EXP2(x) __builtin_amdgcn_exp2f(x)
#else
#define EXP2(x) exp2f(x)
#endif

typedef const void __attribute__((address_space(1)))* gptr_t;
typedef       void __attribute__((address_space(3)))* sptr_t;

// ---------------------------------------------------------------------------
// Kernel 0: W fp32 -> f16 in exact MFMA B-fragment order (unchanged).
// ---------------------------------------------------------------------------
__global__ __launch_bounds__(256) void wconv(
    const float* __restrict__ Wq, const float* __restrict__ Wk,
    const float* __restrict__ Wv, _Float16* __restrict__ whf)
{
    const int idx  = blockIdx.x * 256 + threadIdx.x;
    const int j    = idx & 7;
    const int lane = (idx >> 3) & 63;
    const int et   = (idx >> 9) & 1;
    const int kk   = (idx >> 10) & 7;
    const int eh   = (idx >> 13) & 1;
    const int ph   = idx >> 14;          // p*12 + h
    const int h    = ph % H_;
    const int p    = ph / H_;
    const int e = eh * 32 + et * 16 + (lane & 15);
    const int k = kk * 32 + (lane >> 4) * 8 + j;
    const float* W = (p == 0) ? Wq : (p == 1) ? Wk : Wv;
    whf[idx] = (_Float16)W[((size_t)h * DBLK_ + k) * HD_ + e];
}

// ---------------------------------------------------------------------------
// Kernel 1: block-diagonal QKV projection (R10: V^T staged in LDS, coalesced
// b128 copy-out; global layouts bit-identical to R0).
// ---------------------------------------------------------------------------
__global__ __launch_bounds__(256, 3) void qkv_proj(
    const float* __restrict__ x, const _Float16* __restrict__ whf,
    const float* __restrict__ bq, const float* __restrict__ bk,
    const float* __restrict__ bv,
    _Float16* __restrict__ qo, _Float16* __restrict__ khf,
    _Float16* __restrict__ vtf)
{
    const int i   = blockIdx.x;          // g*128 + sc
    const int g   = i >> 7;              // 0..5
    const int sc  = i & 127;
    const int m   = g >> 1;
    const int s0g = sc * 64;

    const int tid  = threadIdx.x;
    const int lane = tid & 63;
    const int w    = tid >> 6;
    const int ln   = lane & 15;
    const int qd   = lane >> 4;
    const int h    = 2 * g + (w >> 1);
    const int eh   = w & 1;

    // [0,16384): X stage, then Q tiles [0,8192) + K tiles [8192,16384).
    // [16384,24576): V^T tiles (2 ht x 4096). 48KB total, 3 blocks/CU.
    __shared__ _Float16 xs[64 * 256 + 2 * 4096];

    {   // stage X: 64 rows x 256 cols, fp32 -> f16, 16B-granule XOR swizzle
        const int rr   = tid >> 6;
        const int c4   = tid & 63;
        const int g16  = c4 >> 1;
        const int half = c4 & 1;
        #pragma unroll
        for (int pass = 0; pass < 16; pass++) {
            const int r = pass * 4 + rr;
            const float4 v = *(const float4*)(
                x + (size_t)(s0g + r) * HID_ + m * DBLK_ + c4 * 4);
            f16x4 hv;
            hv[0] = (_Float16)v.x; hv[1] = (_Float16)v.y;
            hv[2] = (_Float16)v.z; hv[3] = (_Float16)v.w;
            *(f16x4*)(xs + r * 256 + ((g16 ^ (r & 7)) * 8) + half * 4) = hv;
        }
    }
    __syncthreads();

    f32x4 acc[3][2][4];                  // [p][et][strip]
    #pragma unroll
    for (int p = 0; p < 3; p++)
        #pragma unroll
        for (int et = 0; et < 2; et++)
            #pragma unroll
            for (int st = 0; st < 4; st++)
                acc[p][et][st] = (f32x4){0.f, 0.f, 0.f, 0.f};

    const _Float16* wb = whf + (size_t)((h * 2 + eh) * 16) * 512 + lane * 8;

    for (int kk = 0; kk < 8; kk++) {
        f16x8 a[4];
        #pragma unroll
        for (int st = 0; st < 4; st++)
            a[st] = *(const f16x8*)(
                xs + (st * 16 + ln) * 256 + (((kk * 4 + qd) ^ (ln & 7)) * 8));
        #pragma unroll
        for (int p = 0; p < 3; p++)
            #pragma unroll
            for (int et = 0; et < 2; et++) {
                const f16x8 bb = *(const f16x8*)(
                    wb + (size_t)p * 196608 + (kk * 2 + et) * 512);
                #pragma unroll
                for (int st = 0; st < 4; st++)
                    acc[p][et][st] = __builtin_amdgcn_mfma_f32_16x16x32_f16(
                        a[st], bb, acc[p][et][st], 0, 0, 0);
            }
    }

    const float QS = 0.18033688011112042f;   // 0.125 * log2(e)
    const int b    = s0g >> 11;
    const int s0   = s0g & 2047;
    const int tile = s0 >> 6;
    const int ht   = w >> 1;

    __syncthreads();                      // xs MFMA reads done; reuse as tiles
    // xs layout: Q tiles [ht][64 rows][8 chunks], K at +8192, V^T at +16384.
    // All stored with chunk pos = c ^ (row&7) (V: vc ^ d7). K rows permuted.
    {
        _Float16* qtile = xs + ht * 4096;
        _Float16* ktile = xs + 8192 + ht * 4096;
        _Float16* vtile = xs + 16384 + ht * 4096;
        #pragma unroll
        for (int et = 0; et < 2; et++) {
            const int d  = eh * 32 + et * 16 + ln;
            const int dc = d >> 3, d7 = d & 7;
            const float biasq = bq[h * HD_ + d];
            const float biask = bk[h * HD_ + d];
            const float biasv = bv[h * HD_ + d];
            #pragma unroll
            for (int st = 0; st < 4; st++) {
                // V: into LDS, same swizzled offsets as the global tile
                f16x4 vv;
                #pragma unroll
                for (int r = 0; r < 4; r++) vv[r] = (_Float16)(acc[2][et][st][r] + biasv);
                const int vc = st * 2 + (qd >> 1);
                *(f16x4*)(vtile + d * 64 + ((vc ^ d7) * 8) + (qd & 1) * 4) = vv;
                // Q/K into LDS (transpose staging)
                #pragma unroll
                for (int r = 0; r < 4; r++) {
                    const int sl  = st * 16 + qd * 4 + r;
                    const int rho = (st >> 1) * 32 + (qd & 1) * 16
                                  + ((st & 1) * 2 + (qd >> 1)) * 4 + r;
                    qtile[sl  * 64 + ((dc ^ (sl  & 7)) * 8) + d7] =
                        (_Float16)((acc[0][et][st][r] + biasq) * QS);
                    ktile[rho * 64 + ((dc ^ (rho & 7)) * 8) + d7] =
                        (_Float16)(acc[1][et][st][r] + biask);
                }
            }
        }
    }
    __syncthreads();
    // copy-out: 4 b128 Q + 4 b128 K + 4 b128 V per thread, fully coalesced
    #pragma unroll
    for (int it = 0; it < 4; it++) {
        const int idx  = it * 256 + tid;      // 0..1023
        const int ht2  = idx >> 9;
        const int rest = idx & 511;
        const int row  = rest >> 3;
        const int c    = rest & 7;
        const int bhh2 = b * H_ + 2 * g + ht2;
        // Q: unswizzle (read pos c^(row&7), write chunk c), natural row order
        const f16x8 qv = *(const f16x8*)(xs + ht2 * 4096 + row * 64 + ((c ^ (row & 7)) * 8));
        *(f16x8*)(qo + ((size_t)bhh2 * S_ + s0 + row) * HD_ + c * 8) = qv;
        // K: swizzle is part of the global tile layout -> linear copy
        const f16x8 kv8 = *(const f16x8*)(xs + 8192 + ht2 * 4096 + row * 64 + c * 8);
        *(f16x8*)(khf + (size_t)(bhh2 * 32 + tile) * 4096 + row * 64 + c * 8) = kv8;
        // V: swizzle baked into the LDS tile -> linear copy (row = d here)
        const f16x8 vv8 = *(const f16x8*)(xs + 16384 + ht2 * 4096 + row * 64 + c * 8);
        *(f16x8*)(vtf + (size_t)(bhh2 * 32 + tile) * 4096 + row * 64 + c * 8) = vv8;
    }
}

// ---------------------------------------------------------------------------
// Kernel 2: flash attention — R0 structure + fragment PINNING. The only
// change vs R10: after the 16 ds_read_b128, empty asm pins force kf/vf
// resident, so the MFMA+exp2 stream runs with a single up-front lgkm wait
// instead of per-pair read->wait->MFMA chains (R0 codegen, VGPR_Count=64).
// Per-CU, waves decouple into phase-offset {LDS burst | compute} stages.
// ---------------------------------------------------------------------------
__global__ __launch_bounds__(256, 3) void attn(
    const _Float16* __restrict__ qh, const _Float16* __restrict__ khf,
    const _Float16* __restrict__ vtf, float* __restrict__ out)
{
    const int i    = blockIdx.x;          // 0..767
    const int slot = i >> 3;
    const int bh   = (i & 7) * 6 + (slot % 6);   // XCD-banded bh
    const int qt   = slot / 6;            // 0..15
    const int h = bh % H_, b = bh / H_;
    const int q0 = qt * 128;

    const int tid  = threadIdx.x;
    const int lane = tid & 63;
    const int w    = tid >> 6;
    const int ln   = lane & 15;
    const int qd   = lane >> 4;

    __shared__ __align__(16) char lds[2][16384];   // [buf][ K 8KB | V 8KB ]

    // Q B-frags for this wave's 32-q strip (pre-scaled by 0.125*log2e)
    f16x8 qf[2][2];
    #pragma unroll
    for (int st = 0; st < 2; st++) {
        const _Float16* qb = qh + ((size_t)bh * S_ + q0 + w * 32 + st * 16 + ln) * HD_;
        qf[st][0] = *(const f16x8*)(qb + qd * 8);
        qf[st][1] = *(const f16x8*)(qb + 32 + qd * 8);
    }

    f16x8 ones;
    #pragma unroll
    for (int j = 0; j < 8; j++) ones[j] = (_Float16)1.f;

    f32x4 o[2][4];
    f32x4 lacc[2];
    #pragma unroll
    for (int st = 0; st < 2; st++) {
        lacc[st] = (f32x4){0.f, 0.f, 0.f, 0.f};
        #pragma unroll
        for (int dn = 0; dn < 4; dn++) o[st][dn] = (f32x4){0.f, 0.f, 0.f, 0.f};
    }

    const char* kbase = (const char*)(khf + (size_t)bh * 32 * 4096);
    const char* vbase = (const char*)(vtf + (size_t)bh * 32 * 4096);
    const int   seg   = w * 1024 + lane * 16;
    const int   wseg  = w * 1024;

    auto dma = [&](int it, int buf) {
        const char* ks = kbase + (size_t)it * 8192;
        const char* vs = vbase + (size_t)it * 8192;
        char* lk = &lds[buf][0];
        char* lv = &lds[buf][8192];
        #pragma unroll
        for (int q = 0; q < 2; q++) {
            __builtin_amdgcn_global_load_lds(
                (gptr_t)(ks + q * 4096 + seg), (sptr_t)(lk + q * 4096 + wseg), 16, 0, 0);
            __builtin_amdgcn_global_load_lds(
                (gptr_t)(vs + q * 4096 + seg), (sptr_t)(lv + q * 4096 + wseg), 16, 0, 0);
        }
    };

    dma(0, 0);

    for (int it = 0; it < 32; it++) {
        const int buf = it & 1;
        __syncthreads();
        if (it + 1 < 32) dma(it + 1, buf ^ 1);

        const char* lk = &lds[buf][0];
        const char* lv = &lds[buf][8192];

        // K A-frags (permuted rows baked into the tile): 8 x ds_read_b128
        f16x8 kf[4][2];
        #pragma unroll
        for (int mt = 0; mt < 4; mt++) {
            kf[mt][0] = *(const f16x8*)(lk + (16 * mt + ln) * 128 + ((qd       ^ (ln & 7)) * 16));
            kf[mt][1] = *(const f16x8*)(lk + (16 * mt + ln) * 128 + (((4 + qd) ^ (ln & 7)) * 16));
        }
        // V^T B-frags (K=32): 8 x ds_read_b128
        f16x8 vf[4][2];
        #pragma unroll
        for (int dn = 0; dn < 4; dn++)
            #pragma unroll
            for (int p = 0; p < 2; p++)
                vf[dn][p] = *(const f16x8*)(
                    lv + (dn * 16 + ln) * 128 + (((p * 4 + qd) ^ (ln & 7)) * 16));

        // PIN: force all 16 fragments resident here (one lgkm wait, then the
        // MFMA/exp2 stream below runs LDS-wait-free; defeats the read sink).
        #pragma unroll
        for (int mt = 0; mt < 4; mt++)
            asm volatile("" : "+v"(kf[mt][0]), "+v"(kf[mt][1]));
        #pragma unroll
        for (int dn = 0; dn < 4; dn++)
            asm volatile("" : "+v"(vf[dn][0]), "+v"(vf[dn][1]));

        #pragma unroll
        for (int st = 0; st < 2; st++) {
            f32x4 s[4];
            #pragma unroll
            for (int mt = 0; mt < 4; mt++) {
                s[mt] = (f32x4){0.f, 0.f, 0.f, 0.f};
                s[mt] = __builtin_amdgcn_mfma_f32_16x16x32_f16(kf[mt][0], qf[st][0], s[mt], 0, 0, 0);
                s[mt] = __builtin_amdgcn_mfma_f32_16x16x32_f16(kf[mt][1], qf[st][1], s[mt], 0, 0, 0);
            }
            #pragma unroll
            for (int p = 0; p < 2; p++) {
                // pack two 16x16 S^T tiles into one K=32 P A-frag
                f16x8 a8;
                a8[0] = (_Float16)EXP2(s[2 * p][0]);
                a8[1] = (_Float16)EXP2(s[2 * p][1]);
                a8[2] = (_Float16)EXP2(s[2 * p][2]);
                a8[3] = (_Float16)EXP2(s[2 * p][3]);
                a8[4] = (_Float16)EXP2(s[2 * p + 1][0]);
                a8[5] = (_Float16)EXP2(s[2 * p + 1][1]);
                a8[6] = (_Float16)EXP2(s[2 * p + 1][2]);
                a8[7] = (_Float16)EXP2(s[2 * p + 1][3]);
                lacc[st] = __builtin_amdgcn_mfma_f32_16x16x32_f16(a8, ones, lacc[st], 0, 0, 0);
                #pragma unroll
                for (int dn = 0; dn < 4; dn++)
                    o[st][dn] = __builtin_amdgcn_mfma_f32_16x16x32_f16(
                        a8, vf[dn][p], o[st][dn], 0, 0, 0);
            }
        }
    }

    // epilogue: l is already row-aligned with O -> no shuffles at all
    #pragma unroll
    for (int st = 0; st < 2; st++) {
        float inv[4];
        #pragma unroll
        for (int r = 0; r < 4; r++) inv[r] = 1.f / lacc[st][r];
        #pragma unroll
        for (int dn = 0; dn < 4; dn++) {
            float* op = out + ((size_t)b * S_ + q0 + w * 32 + st * 16 + qd * 4) * HID_
                      + (size_t)h * HD_ + dn * 16 + ln;
            #pragma unroll
            for (int r = 0; r < 4; r++)
                op[(size_t)r * HID_] = o[st][dn][r] * inv[r];
        }
    }
}

// ---------------------------------------------------------------------------
extern "C" void kernel_launch(void* const* d_in, const int* in_sizes, int n_in,
                              void* d_out, int out_size, void* d_ws, size_t ws_size,
                              hipStream_t stream) {
    const float* x  = (const float*)d_in[0];
    const float* Wq = (const float*)d_in[1];
    const float* bq = (const float*)d_in[2];
    const float* Wk = (const float*)d_in[3];
    const float* bk = (const float*)d_in[4];
    const float* Wv = (const float*)d_in[5];
    const float* bv = (const float*)d_in[6];
    float* out = (float*)d_out;

    _Float16* q  = (_Float16*)d_ws;
    _Float16* k  = q + QSZ_;
    _Float16* vt = k + QSZ_;
    const size_t need = ((size_t)3 * QSZ_ + WTSZ_) * sizeof(_Float16);
    _Float16* wh = (ws_size >= need) ? (vt + QSZ_)
                                     : (_Float16*)d_out;  // consumed before attn writes out

    wconv<<<WTSZ_ / 256, 256, 0, stream>>>(Wq, Wk, Wv, wh);
    qkv_proj<<<768, 256, 0, stream>>>(x, wh, bq, bk, bv, q, k, vt);
    attn<<<768, 256, 0, stream>>>(q, k, vt, out);
}

// Round 13
// 155.365 us; speedup vs baseline: 1.0501x; 1.0501x over previous
//
#include <hip/hip_runtime.h>
#include <hip/hip_bf16.h>

// ============================================================================
// R13 = R10 verbatim (proven best: 159.5us total; attn 54.8us, 0 conflicts,
// VGPR 64; qkv_proj with V^T staged through LDS -> coalesced b128 stores).
//
// FROZEN. Exploration ledger (R1-R12; do not retry without new evidence):
//  - 32x32x16 MFMA variants: deterministic 4cy/read LDS conflict tax (R1 61us,
//    R3 68us with wave-split).
//  - l-accumulator on VALU: flat pipe demand, +5us — lacc MFMAs were hiding
//    latency (R5).
//  - s_setprio: regresses lockstep 4-wave blocks (R4; m190 regime).
//  - cross-tile register pipeline: occ-3 -> compiler re-sinks (R6 neutral);
//    occ-2 -> 235-VGPR state spills (R7, 1.17GB scratch) or races (R8,
//    absmax 6.6e-3).
//  - asm fragment pins: pairwise-ordered -> interleaved anyway, -2.5us (R11).
//  - s_sleep phase stagger: correctness failure (R12, absmax 2.9e-3) —
//    timing-only change failing implies a latent timing window; the entire
//    timing-perturbation class is closed (2 failures, 0 wins).
// attn: MFMA 46% + VALU 44% ~ 90% combined issue, 941 TF effective (38% of
// dense bf16 peak), conflict-free — the compiler's register-minimizing
// schedule enforces read->wait->MFMA alternation that HIP source cannot
// break on this structure without spill/race.
// ============================================================================

#define B_    4
#define S_    2048
#define HID_  768
#define H_    12
#define DBLK_ 256
#define HD_   64
#define BH_   (B_ * H_)                 // 48
#define QSZ_  (B_ * H_ * S_ * HD_)      // 6291456 elements
#define WTSZ_ (3 * H_ * HD_ * DBLK_)    // 589824 elements

typedef _Float16 f16x4 __attribute__((ext_vector_type(4)));
typedef _Float16 f16x8 __attribute__((ext_vector_type(8)));
typedef float    f32x4 __attribute__((ext_vector_type(4)));

#if __has_builtin(__builtin_amdgcn_exp2f)
#define EXP2(x) __builtin_amdgcn_exp2f(x)
#else
#define EXP2(x) exp2f(x)
#endif

typedef const void __attribute__((address_space(1)))* gptr_t;
typedef       void __attribute__((address_space(3)))* sptr_t;

// ---------------------------------------------------------------------------
// Kernel 0: W fp32 -> f16 in exact MFMA B-fragment order.
// ---------------------------------------------------------------------------
__global__ __launch_bounds__(256) void wconv(
    const float* __restrict__ Wq, const float* __restrict__ Wk,
    const float* __restrict__ Wv, _Float16* __restrict__ whf)
{
    const int idx  = blockIdx.x * 256 + threadIdx.x;
    const int j    = idx & 7;
    const int lane = (idx >> 3) & 63;
    const int et   = (idx >> 9) & 1;
    const int kk   = (idx >> 10) & 7;
    const int eh   = (idx >> 13) & 1;
    const int ph   = idx >> 14;          // p*12 + h
    const int h    = ph % H_;
    const int p    = ph / H_;
    const int e = eh * 32 + et * 16 + (lane & 15);
    const int k = kk * 32 + (lane >> 4) * 8 + j;
    const float* W = (p == 0) ? Wq : (p == 1) ? Wk : Wv;
    whf[idx] = (_Float16)W[((size_t)h * DBLK_ + k) * HD_ + e];
}

// ---------------------------------------------------------------------------
// Kernel 1: block-diagonal QKV projection. K tile rows stored in PERMUTED
// order (rho); K/V tiles chunk-XOR-swizzled so attn's post-DMA LDS reads are
// conflict-free. V^T staged through LDS -> fully coalesced b128 copy-out.
// ---------------------------------------------------------------------------
__global__ __launch_bounds__(256, 3) void qkv_proj(
    const float* __restrict__ x, const _Float16* __restrict__ whf,
    const float* __restrict__ bq, const float* __restrict__ bk,
    const float* __restrict__ bv,
    _Float16* __restrict__ qo, _Float16* __restrict__ khf,
    _Float16* __restrict__ vtf)
{
    const int i   = blockIdx.x;          // g*128 + sc
    const int g   = i >> 7;              // 0..5
    const int sc  = i & 127;
    const int m   = g >> 1;
    const int s0g = sc * 64;

    const int tid  = threadIdx.x;
    const int lane = tid & 63;
    const int w    = tid >> 6;
    const int ln   = lane & 15;
    const int qd   = lane >> 4;
    const int h    = 2 * g + (w >> 1);
    const int eh   = w & 1;

    // [0,16384): X stage, then Q tiles [0,8192) + K tiles [8192,16384).
    // [16384,24576): V^T tiles (2 ht x 4096). 48KB total, 3 blocks/CU.
    __shared__ _Float16 xs[64 * 256 + 2 * 4096];

    {   // stage X: 64 rows x 256 cols, fp32 -> f16, 16B-granule XOR swizzle
        const int rr   = tid >> 6;
        const int c4   = tid & 63;
        const int g16  = c4 >> 1;
        const int half = c4 & 1;
        #pragma unroll
        for (int pass = 0; pass < 16; pass++) {
            const int r = pass * 4 + rr;
            const float4 v = *(const float4*)(
                x + (size_t)(s0g + r) * HID_ + m * DBLK_ + c4 * 4);
            f16x4 hv;
            hv[0] = (_Float16)v.x; hv[1] = (_Float16)v.y;
            hv[2] = (_Float16)v.z; hv[3] = (_Float16)v.w;
            *(f16x4*)(xs + r * 256 + ((g16 ^ (r & 7)) * 8) + half * 4) = hv;
        }
    }
    __syncthreads();

    f32x4 acc[3][2][4];                  // [p][et][strip]
    #pragma unroll
    for (int p = 0; p < 3; p++)
        #pragma unroll
        for (int et = 0; et < 2; et++)
            #pragma unroll
            for (int st = 0; st < 4; st++)
                acc[p][et][st] = (f32x4){0.f, 0.f, 0.f, 0.f};

    const _Float16* wb = whf + (size_t)((h * 2 + eh) * 16) * 512 + lane * 8;

    for (int kk = 0; kk < 8; kk++) {
        f16x8 a[4];
        #pragma unroll
        for (int st = 0; st < 4; st++)
            a[st] = *(const f16x8*)(
                xs + (st * 16 + ln) * 256 + (((kk * 4 + qd) ^ (ln & 7)) * 8));
        #pragma unroll
        for (int p = 0; p < 3; p++)
            #pragma unroll
            for (int et = 0; et < 2; et++) {
                const f16x8 bb = *(const f16x8*)(
                    wb + (size_t)p * 196608 + (kk * 2 + et) * 512);
                #pragma unroll
                for (int st = 0; st < 4; st++)
                    acc[p][et][st] = __builtin_amdgcn_mfma_f32_16x16x32_f16(
                        a[st], bb, acc[p][et][st], 0, 0, 0);
            }
    }

    const float QS = 0.18033688011112042f;   // 0.125 * log2(e)
    const int b    = s0g >> 11;
    const int s0   = s0g & 2047;
    const int tile = s0 >> 6;
    const int ht   = w >> 1;

    __syncthreads();                      // xs MFMA reads done; reuse as tiles
    // xs layout: Q tiles [ht][64 rows][8 chunks], K at +8192, V^T at +16384.
    // All stored with chunk pos = c ^ (row&7) (V: vc ^ d7). K rows permuted.
    {
        _Float16* qtile = xs + ht * 4096;
        _Float16* ktile = xs + 8192 + ht * 4096;
        _Float16* vtile = xs + 16384 + ht * 4096;
        #pragma unroll
        for (int et = 0; et < 2; et++) {
            const int d  = eh * 32 + et * 16 + ln;
            const int dc = d >> 3, d7 = d & 7;
            const float biasq = bq[h * HD_ + d];
            const float biask = bk[h * HD_ + d];
            const float biasv = bv[h * HD_ + d];
            #pragma unroll
            for (int st = 0; st < 4; st++) {
                // V: into LDS, same swizzled offsets as the global tile
                f16x4 vv;
                #pragma unroll
                for (int r = 0; r < 4; r++) vv[r] = (_Float16)(acc[2][et][st][r] + biasv);
                const int vc = st * 2 + (qd >> 1);
                *(f16x4*)(vtile + d * 64 + ((vc ^ d7) * 8) + (qd & 1) * 4) = vv;
                // Q/K into LDS (transpose staging)
                #pragma unroll
                for (int r = 0; r < 4; r++) {
                    const int sl  = st * 16 + qd * 4 + r;
                    const int rho = (st >> 1) * 32 + (qd & 1) * 16
                                  + ((st & 1) * 2 + (qd >> 1)) * 4 + r;
                    qtile[sl  * 64 + ((dc ^ (sl  & 7)) * 8) + d7] =
                        (_Float16)((acc[0][et][st][r] + biasq) * QS);
                    ktile[rho * 64 + ((dc ^ (rho & 7)) * 8) + d7] =
                        (_Float16)(acc[1][et][st][r] + biask);
                }
            }
        }
    }
    __syncthreads();
    // copy-out: 4 b128 Q + 4 b128 K + 4 b128 V per thread, fully coalesced
    #pragma unroll
    for (int it = 0; it < 4; it++) {
        const int idx  = it * 256 + tid;      // 0..1023
        const int ht2  = idx >> 9;
        const int rest = idx & 511;
        const int row  = rest >> 3;
        const int c    = rest & 7;
        const int bhh2 = b * H_ + 2 * g + ht2;
        // Q: unswizzle (read pos c^(row&7), write chunk c), natural row order
        const f16x8 qv = *(const f16x8*)(xs + ht2 * 4096 + row * 64 + ((c ^ (row & 7)) * 8));
        *(f16x8*)(qo + ((size_t)bhh2 * S_ + s0 + row) * HD_ + c * 8) = qv;
        // K: swizzle is part of the global tile layout -> linear copy
        const f16x8 kv8 = *(const f16x8*)(xs + 8192 + ht2 * 4096 + row * 64 + c * 8);
        *(f16x8*)(khf + (size_t)(bhh2 * 32 + tile) * 4096 + row * 64 + c * 8) = kv8;
        // V: swizzle baked into the LDS tile -> linear copy (row = d here)
        const f16x8 vv8 = *(const f16x8*)(xs + 16384 + ht2 * 4096 + row * 64 + c * 8);
        *(f16x8*)(vtf + (size_t)(bhh2 * 32 + tile) * 4096 + row * 64 + c * 8) = vv8;
    }
}

// ---------------------------------------------------------------------------
// Kernel 2: flash attention, q-split (128 q/block, 32 q/wave), kv tiles of 64.
// K+V tiles DMA'd to double-buffered LDS (global_load_lds w=16), 1 barrier/it.
// Permuted K rows make S^T-tile pairs pack into K=32 PV A-frags: ALL MFMA are
// 16x16x32. l accumulated via MFMA against all-ones B; its C-layout aligns
// with O's rows -> shuffle-free epilogue.
// ---------------------------------------------------------------------------
__global__ __launch_bounds__(256, 3) void attn(
    const _Float16* __restrict__ qh, const _Float16* __restrict__ khf,
    const _Float16* __restrict__ vtf, float* __restrict__ out)
{
    const int i    = blockIdx.x;          // 0..767
    const int slot = i >> 3;
    const int bh   = (i & 7) * 6 + (slot % 6);   // XCD-banded bh
    const int qt   = slot / 6;            // 0..15
    const int h = bh % H_, b = bh / H_;
    const int q0 = qt * 128;

    const int tid  = threadIdx.x;
    const int lane = tid & 63;
    const int w    = tid >> 6;
    const int ln   = lane & 15;
    const int qd   = lane >> 4;

    __shared__ __align__(16) char lds[2][16384];   // [buf][ K 8KB | V 8KB ]

    // Q B-frags for this wave's 32-q strip (pre-scaled by 0.125*log2e)
    f16x8 qf[2][2];
    #pragma unroll
    for (int st = 0; st < 2; st++) {
        const _Float16* qb = qh + ((size_t)bh * S_ + q0 + w * 32 + st * 16 + ln) * HD_;
        qf[st][0] = *(const f16x8*)(qb + qd * 8);
        qf[st][1] = *(const f16x8*)(qb + 32 + qd * 8);
    }

    f16x8 ones;
    #pragma unroll
    for (int j = 0; j < 8; j++) ones[j] = (_Float16)1.f;

    f32x4 o[2][4];
    f32x4 lacc[2];
    #pragma unroll
    for (int st = 0; st < 2; st++) {
        lacc[st] = (f32x4){0.f, 0.f, 0.f, 0.f};
        #pragma unroll
        for (int dn = 0; dn < 4; dn++) o[st][dn] = (f32x4){0.f, 0.f, 0.f, 0.f};
    }

    const char* kbase = (const char*)(khf + (size_t)bh * 32 * 4096);
    const char* vbase = (const char*)(vtf + (size_t)bh * 32 * 4096);
    const int   seg   = w * 1024 + lane * 16;
    const int   wseg  = w * 1024;

    auto dma = [&](int it, int buf) {
        const char* ks = kbase + (size_t)it * 8192;
        const char* vs = vbase + (size_t)it * 8192;
        char* lk = &lds[buf][0];
        char* lv = &lds[buf][8192];
        #pragma unroll
        for (int q = 0; q < 2; q++) {
            __builtin_amdgcn_global_load_lds(
                (gptr_t)(ks + q * 4096 + seg), (sptr_t)(lk + q * 4096 + wseg), 16, 0, 0);
            __builtin_amdgcn_global_load_lds(
                (gptr_t)(vs + q * 4096 + seg), (sptr_t)(lv + q * 4096 + wseg), 16, 0, 0);
        }
    };

    dma(0, 0);

    for (int it = 0; it < 32; it++) {
        const int buf = it & 1;
        __syncthreads();
        if (it + 1 < 32) dma(it + 1, buf ^ 1);

        const char* lk = &lds[buf][0];
        const char* lv = &lds[buf][8192];

        // K A-frags (permuted rows baked into the tile): 8 x ds_read_b128
        f16x8 kf[4][2];
        #pragma unroll
        for (int mt = 0; mt < 4; mt++) {
            kf[mt][0] = *(const f16x8*)(lk + (16 * mt + ln) * 128 + ((qd       ^ (ln & 7)) * 16));
            kf[mt][1] = *(const f16x8*)(lk + (16 * mt + ln) * 128 + (((4 + qd) ^ (ln & 7)) * 16));
        }
        // V^T B-frags (K=32): 8 x ds_read_b128
        f16x8 vf[4][2];
        #pragma unroll
        for (int dn = 0; dn < 4; dn++)
            #pragma unroll
            for (int p = 0; p < 2; p++)
                vf[dn][p] = *(const f16x8*)(
                    lv + (dn * 16 + ln) * 128 + (((p * 4 + qd) ^ (ln & 7)) * 16));

        #pragma unroll
        for (int st = 0; st < 2; st++) {
            f32x4 s[4];
            #pragma unroll
            for (int mt = 0; mt < 4; mt++) {
                s[mt] = (f32x4){0.f, 0.f, 0.f, 0.f};
                s[mt] = __builtin_amdgcn_mfma_f32_16x16x32_f16(kf[mt][0], qf[st][0], s[mt], 0, 0, 0);
                s[mt] = __builtin_amdgcn_mfma_f32_16x16x32_f16(kf[mt][1], qf[st][1], s[mt], 0, 0, 0);
            }
            #pragma unroll
            for (int p = 0; p < 2; p++) {
                // pack two 16x16 S^T tiles into one K=32 P A-frag
                f16x8 a8;
                a8[0] = (_Float16)EXP2(s[2 * p][0]);
                a8[1] = (_Float16)EXP2(s[2 * p][1]);
                a8[2] = (_Float16)EXP2(s[2 * p][2]);
                a8[3] = (_Float16)EXP2(s[2 * p][3]);
                a8[4] = (_Float16)EXP2(s[2 * p + 1][0]);
                a8[5] = (_Float16)EXP2(s[2 * p + 1][1]);
                a8[6] = (_Float16)EXP2(s[2 * p + 1][2]);
                a8[7] = (_Float16)EXP2(s[2 * p + 1][3]);
                lacc[st] = __builtin_amdgcn_mfma_f32_16x16x32_f16(a8, ones, lacc[st], 0, 0, 0);
                #pragma unroll
                for (int dn = 0; dn < 4; dn++)
                    o[st][dn] = __builtin_amdgcn_mfma_f32_16x16x32_f16(
                        a8, vf[dn][p], o[st][dn], 0, 0, 0);
            }
        }
    }

    // epilogue: l is already row-aligned with O -> no shuffles at all
    #pragma unroll
    for (int st = 0; st < 2; st++) {
        float inv[4];
        #pragma unroll
        for (int r = 0; r < 4; r++) inv[r] = 1.f / lacc[st][r];
        #pragma unroll
        for (int dn = 0; dn < 4; dn++) {
            float* op = out + ((size_t)b * S_ + q0 + w * 32 + st * 16 + qd * 4) * HID_
                      + (size_t)h * HD_ + dn * 16 + ln;
            #pragma unroll
            for (int r = 0; r < 4; r++)
                op[(size_t)r * HID_] = o[st][dn][r] * inv[r];
        }
    }
}

// ---------------------------------------------------------------------------
extern "C" void kernel_launch(void* const* d_in, const int* in_sizes, int n_in,
                              void* d_out, int out_size, void* d_ws, size_t ws_size,
                              hipStream_t stream) {
    const float* x  = (const float*)d_in[0];
    const float* Wq = (const float*)d_in[1];
    const float* bq = (const float*)d_in[2];
    const float* Wk = (const float*)d_in[3];
    const float* bk = (const float*)d_in[4];
    const float* Wv = (const float*)d_in[5];
    const float* bv = (const float*)d_in[6];
    float* out = (float*)d_out;

    _Float16* q  = (_Float16*)d_ws;
    _Float16* k  = q + QSZ_;
    _Float16* vt = k + QSZ_;
    const size_t need = ((size_t)3 * QSZ_ + WTSZ_) * sizeof(_Float16);
    _Float16* wh = (ws_size >= need) ? (vt + QSZ_)
                                     : (_Float16*)d_out;  // consumed before attn writes out

    wconv<<<WTSZ_ / 256, 256, 0, stream>>>(Wq, Wk, Wv, wh);
    qkv_proj<<<768, 256, 0, stream>>>(x, wh, bq, bk, bv, q, k, vt);
    attn<<<768, 256, 0, stream>>>(q, k, vt, out);
}